// Round 1
// baseline (1727.229 us; speedup 1.0000x reference)
//
#include <hip/hip_runtime.h>

// LSTM: T=4096 steps, B=512 batch, NIN=42, NH=9.
// Kernel 1 (proj): P[t][b][j*4+g] = x[t][b]·W_ih[g*9+j] + b_ih[g*9+j] + b_hh[g*9+j]
//   (gate-permuted so lane j reads its 4 gates as one float4)
// Kernel 2 (lstm): 512 independent chains; 16 lanes/chain (9 active), 4 chains per
//   64-thread block; h exchanged via double-buffered LDS; 8-deep P prefetch ring.
// d_ws layout: P = T*B*36 floats = 301,989,888 bytes.

#define TT 4096
#define BB 512
#define NIN 42
#define NH 9
#define G4 36
#define PF 8

__device__ __forceinline__ float fast_sigmoid(float x) {
  // 1/(1+e^-x) = rcp(1 + 2^(-x*log2e))
  float e = __builtin_amdgcn_exp2f(-1.4426950408889634f * x);
  return __builtin_amdgcn_rcpf(1.0f + e);
}
__device__ __forceinline__ float fast_tanh(float x) {
  // 1 - 2/(e^{2x}+1); safe at +/-inf of the exp
  float e = __builtin_amdgcn_exp2f(2.8853900817779268f * x);
  return 1.0f - 2.0f * __builtin_amdgcn_rcpf(1.0f + e);
}

__global__ __launch_bounds__(256) void proj_kernel(
    const float* __restrict__ x, const float* __restrict__ W_ih,
    const float* __restrict__ b_ih, const float* __restrict__ b_hh,
    float* __restrict__ P) {
  __shared__ float Wt[NIN][G4];   // Wt[k][j*4+g] = W_ih[(g*9+j)*42 + k]
  __shared__ float bias[G4];
  for (int idx = threadIdx.x; idx < NIN * G4; idx += 256) {
    int k = idx / G4, m = idx - k * G4;
    int j = m >> 2, g = m & 3;
    Wt[k][m] = W_ih[(g * NH + j) * NIN + k];
  }
  if (threadIdx.x < G4) {
    int m = threadIdx.x, j = m >> 2, g = m & 3;
    bias[m] = b_ih[g * NH + j] + b_hh[g * NH + j];
  }
  __syncthreads();

  int row = blockIdx.x * 256 + threadIdx.x;   // grid covers T*B rows exactly
  const float* xr = x + (size_t)row * NIN;
  float xv[NIN];
#pragma unroll
  for (int k = 0; k < NIN; k++) xv[k] = xr[k];

  float acc[G4];
#pragma unroll
  for (int m = 0; m < G4; m++) acc[m] = bias[m];
#pragma unroll
  for (int k = 0; k < NIN; k++) {
#pragma unroll
    for (int m = 0; m < G4; m++) acc[m] += xv[k] * Wt[k][m];
  }

  float4* o = (float4*)(P + (size_t)row * G4);  // 144B rows -> 16B aligned
#pragma unroll
  for (int q = 0; q < NH; q++)
    o[q] = make_float4(acc[4 * q], acc[4 * q + 1], acc[4 * q + 2], acc[4 * q + 3]);
}

__global__ __launch_bounds__(64) void lstm_kernel(
    const float* __restrict__ P, const float* __restrict__ h0,
    const float* __restrict__ c0, const float* __restrict__ W_hh,
    float* __restrict__ out) {
  const int lane = threadIdx.x;
  const int cl = lane >> 4;          // chain-local 0..3
  const int j = lane & 15;           // hidden unit, active if < 9
  const bool act = (j < NH);
  const int jj = act ? j : 0;
  const int b = blockIdx.x * 4 + cl; // batch chain 0..511

  __shared__ float hbuf[2][4][16];

  // W[g][k] = W_hh[(g*9+j)*9 + k] ; gate order i,f,g,o
  float W[4][NH];
#pragma unroll
  for (int g = 0; g < 4; g++)
#pragma unroll
    for (int k = 0; k < NH; k++) W[g][k] = W_hh[(g * NH + jj) * NH + k];

  float h = h0[b * NH + jj];
  float c = c0[b * NH + jj];
  hbuf[0][cl][j] = act ? h : 0.0f;
  __syncthreads();

  const float4* Pv = (const float4*)P;
  const size_t stride = (size_t)BB * NH;       // 4608: float4s per t (and floats per out row)
  const size_t base = (size_t)b * NH + jj;     // float4 index within a t-slab

  float4 pre[PF];
#pragma unroll
  for (int i = 0; i < PF; i++) pre[i] = Pv[(size_t)i * stride + base];

  for (int t0 = 0; t0 < TT; t0 += PF) {
#pragma unroll
    for (int u = 0; u < PF; u++) {
      const int t = t0 + u;
      const int pr = u & 1;                    // == t & 1 (PF even)
      float4 p = pre[u];
      float gi = p.x, gf = p.y, gg = p.z, go = p.w;
#pragma unroll
      for (int k = 0; k < NH; k++) {
        float hk = hbuf[pr][cl][k];
        gi += W[0][k] * hk;
        gf += W[1][k] * hk;
        gg += W[2][k] * hk;
        go += W[3][k] * hk;
      }
      float i_ = fast_sigmoid(gi);
      float f_ = fast_sigmoid(gf);
      float g_ = fast_tanh(gg);
      float o_ = fast_sigmoid(go);
      c = f_ * c + i_ * g_;
      h = o_ * fast_tanh(c);
      if (act) out[(size_t)t * stride + base] = h;
      // prefetch t+PF (clamped; tail values unused)
      int tn = t + PF;
      if (tn > TT - 1) tn = TT - 1;
      pre[u] = Pv[(size_t)tn * stride + base];
      // publish h for step t+1 (other buffer); one barrier orders write->read
      hbuf[pr ^ 1][cl][j] = h;
      __syncthreads();
    }
  }

  if (act) {
    out[(size_t)TT * stride + (size_t)b * NH + j] = h;                       // hn
    out[(size_t)TT * stride + (size_t)BB * NH + (size_t)b * NH + j] = c;     // cn
  }
}

extern "C" void kernel_launch(void* const* d_in, const int* in_sizes, int n_in,
                              void* d_out, int out_size, void* d_ws, size_t ws_size,
                              hipStream_t stream) {
  (void)in_sizes; (void)n_in; (void)out_size; (void)ws_size;
  const float* x    = (const float*)d_in[0];
  const float* h0   = (const float*)d_in[1];
  const float* c0   = (const float*)d_in[2];
  const float* W_ih = (const float*)d_in[3];
  const float* W_hh = (const float*)d_in[4];
  const float* b_ih = (const float*)d_in[5];
  const float* b_hh = (const float*)d_in[6];
  float* out = (float*)d_out;
  float* P   = (float*)d_ws;  // needs 302 MB of workspace

  proj_kernel<<<(TT * BB) / 256, 256, 0, stream>>>(x, W_ih, b_ih, b_hh, P);
  lstm_kernel<<<BB / 4, 64, 0, stream>>>(P, h0, c0, W_hh, out);
}

// Round 2
// 1355.336 us; speedup vs baseline: 1.2744x; 1.2744x over previous
//
#include <hip/hip_runtime.h>

// LSTM: T=4096, B=512, NIN=42, NH=9.
// proj: P[row][j*4+g] = x[row]·W_ih[g*9+j] + b_ih + b_hh   (row = t*B+b; gate-permuted
//       so each lstm lane reads its 4 gates as one float4). x staged via LDS (coalesced);
//       W read wave-uniform from global -> s_load path.
// lstm: 512 chains; 16 lanes/chain (9 active), 4 chains per 64-thread (single-wave) block.
//       NO barriers: h exchanged with ds_swizzle broadcasts (register-only). 8-deep P
//       prefetch ring stays in flight since nothing drains vmcnt.
// d_ws: P = 4096*512*36 floats = 301,989,888 bytes.

#define TT 4096
#define BB 512
#define NIN 42
#define NH 9
#define G4 36
#define PF 8

typedef float v2f __attribute__((ext_vector_type(2)));

__device__ __forceinline__ float fast_sigmoid(float x) {
  float e = __builtin_amdgcn_exp2f(-1.4426950408889634f * x);
  return __builtin_amdgcn_rcpf(1.0f + e);
}
__device__ __forceinline__ float fast_tanh(float x) {
  float e = __builtin_amdgcn_exp2f(2.8853900817779268f * x);
  return 1.0f - 2.0f * __builtin_amdgcn_rcpf(1.0f + e);
}

// broadcast lane (group16_base + k) to all lanes of its 16-group; k literal
#define BCAST16(dst, src, k)                                                   \
  dst = __int_as_float(__builtin_amdgcn_ds_swizzle(__float_as_int(src),        \
                                                   ((k) << 5) | 0x10))

__global__ __launch_bounds__(256) void proj_kernel(
    const float* __restrict__ x, const float* __restrict__ W_ih,
    const float* __restrict__ b_ih, const float* __restrict__ b_hh,
    float* __restrict__ P) {
  __shared__ float xs[256 * NIN];  // 43008 B, unpadded (stage = linear float4)
  const int tid = threadIdx.x;
  const size_t rowBase = (size_t)blockIdx.x * 256;

  // ---- stage x: 2688 float4 per block, fully coalesced ----
  const float4* xv4 = (const float4*)(x + rowBase * NIN);  // 43008B/block: 16B aligned
  float4* xs4 = (float4*)xs;
#pragma unroll
  for (int it = 0; it < 11; ++it) {
    int idx = tid + it * 256;
    if (idx < 2688) xs4[idx] = xv4[idx];
  }
  __syncthreads();

  // ---- compute: one row per thread; W via wave-uniform global reads ----
  float acc[G4];
#pragma unroll
  for (int m = 0; m < G4; m++) {
    int j = m >> 2, g = m & 3;
    acc[m] = b_ih[g * NH + j] + b_hh[g * NH + j];  // uniform -> scalar loads
  }
  const float* xr = xs + tid * NIN;
#pragma unroll
  for (int k = 0; k < NIN; k++) {
    float xk = xr[k];
#pragma unroll
    for (int m = 0; m < G4; m++) {
      int j = m >> 2, g = m & 3;
      acc[m] += xk * W_ih[(g * NH + j) * NIN + k];  // uniform addr -> s_load
    }
  }

  float4* o = (float4*)(P + (rowBase + tid) * (size_t)G4);
#pragma unroll
  for (int q = 0; q < NH; q++)
    o[q] = make_float4(acc[4 * q], acc[4 * q + 1], acc[4 * q + 2], acc[4 * q + 3]);
}

__global__ __launch_bounds__(64) void lstm_kernel(
    const float* __restrict__ P, const float* __restrict__ h0,
    const float* __restrict__ c0, const float* __restrict__ W_hh,
    float* __restrict__ out) {
  const int lane = threadIdx.x;
  const int cl = lane >> 4;
  const int j = lane & 15;
  const bool act = (j < NH);
  const int jj = act ? j : 0;
  const int b = blockIdx.x * 4 + cl;

  // packed weights: Wif[k] = (W_i[j][k], W_f[j][k]), Wgo[k] = (W_g[j][k], W_o[j][k])
  v2f Wif[NH], Wgo[NH];
#pragma unroll
  for (int k = 0; k < NH; k++) {
    Wif[k] = (v2f){W_hh[(0 * NH + jj) * NH + k], W_hh[(1 * NH + jj) * NH + k]};
    Wgo[k] = (v2f){W_hh[(2 * NH + jj) * NH + k], W_hh[(3 * NH + jj) * NH + k]};
  }

  float h = h0[b * NH + jj];
  float c = c0[b * NH + jj];

  const float4* Pv = (const float4*)P;
  const size_t stride = (size_t)BB * NH;   // 4608
  const size_t base = (size_t)b * NH + jj;

  float4 pre[PF];
#pragma unroll
  for (int i = 0; i < PF; i++) pre[i] = Pv[(size_t)i * stride + base];

  for (int t0 = 0; t0 < TT; t0 += PF) {
#pragma unroll
    for (int u = 0; u < PF; u++) {
      const int t = t0 + u;
      float4 p = pre[u];
      // broadcast previous h of all 9 units in this chain (register-only exchange)
      float h0r, h1r, h2r, h3r, h4r, h5r, h6r, h7r, h8r;
      BCAST16(h0r, h, 0); BCAST16(h1r, h, 1); BCAST16(h2r, h, 2);
      BCAST16(h3r, h, 3); BCAST16(h4r, h, 4); BCAST16(h5r, h, 5);
      BCAST16(h6r, h, 6); BCAST16(h7r, h, 7); BCAST16(h8r, h, 8);

      v2f a0 = (v2f){p.x, p.y} + Wif[0] * h0r;
      v2f a1 = Wif[1] * h1r;
      v2f a2 = Wif[2] * h2r;
      a0 += Wif[3] * h3r; a1 += Wif[4] * h4r; a2 += Wif[5] * h5r;
      a0 += Wif[6] * h6r; a1 += Wif[7] * h7r; a2 += Wif[8] * h8r;
      v2f gif = (a0 + a1) + a2;

      v2f d0 = (v2f){p.z, p.w} + Wgo[0] * h0r;
      v2f d1 = Wgo[1] * h1r;
      v2f d2 = Wgo[2] * h2r;
      d0 += Wgo[3] * h3r; d1 += Wgo[4] * h4r; d2 += Wgo[5] * h5r;
      d0 += Wgo[6] * h6r; d1 += Wgo[7] * h7r; d2 += Wgo[8] * h8r;
      v2f ggo = (d0 + d1) + d2;

      float i_ = fast_sigmoid(gif.x);
      float f_ = fast_sigmoid(gif.y);
      float g_ = fast_tanh(ggo.x);
      float o_ = fast_sigmoid(ggo.y);
      c = f_ * c + i_ * g_;
      h = o_ * fast_tanh(c);
      if (act) out[(size_t)t * stride + base] = h;

      int tn = t + PF;                 // prefetch (clamped; tail unused)
      if (tn > TT - 1) tn = TT - 1;
      pre[u] = Pv[(size_t)tn * stride + base];
    }
  }

  if (act) {
    out[(size_t)TT * stride + (size_t)b * NH + j] = h;                    // hn
    out[(size_t)TT * stride + stride + (size_t)b * NH + j] = c;           // cn
  }
}

extern "C" void kernel_launch(void* const* d_in, const int* in_sizes, int n_in,
                              void* d_out, int out_size, void* d_ws, size_t ws_size,
                              hipStream_t stream) {
  (void)in_sizes; (void)n_in; (void)out_size; (void)ws_size;
  const float* x    = (const float*)d_in[0];
  const float* h0   = (const float*)d_in[1];
  const float* c0   = (const float*)d_in[2];
  const float* W_ih = (const float*)d_in[3];
  const float* W_hh = (const float*)d_in[4];
  const float* b_ih = (const float*)d_in[5];
  const float* b_hh = (const float*)d_in[6];
  float* out = (float*)d_out;
  float* P   = (float*)d_ws;  // 302 MB workspace

  proj_kernel<<<(TT * BB) / 256, 256, 0, stream>>>(x, W_ih, b_ih, b_hh, P);
  lstm_kernel<<<BB / 4, 64, 0, stream>>>(P, h0, c0, W_hh, out);
}